// Round 15
// baseline (248.286 us; speedup 1.0000x reference)
//
#include <hip/hip_runtime.h>
#include <stdint.h>

typedef unsigned short u16;
typedef float f32x16 __attribute__((ext_vector_type(16)));
typedef float f32x4v __attribute__((ext_vector_type(4)));   // clang vector: nt-load legal
typedef short s16x8 __attribute__((ext_vector_type(8)));

#define K_DIM 768      // C = K for all GEMMs
#define M_ROWS 32768   // B*NQ
#define NQ_ 16384
#define HW_ 128

__device__ __forceinline__ float bf2f(u16 u) {
    union { uint32_t u; float f; } c; c.u = ((uint32_t)u) << 16; return c.f;
}
__device__ __forceinline__ u16 f2bf(float f) {
    union { float f; uint32_t u; } c; c.f = f;
    uint32_t u = c.u;
    u += 0x7FFFu + ((u >> 16) & 1);   // round-to-nearest-even
    return (u16)(u >> 16);
}

__device__ __forceinline__ void gload_lds16(const void* g, void* l) {
    __builtin_amdgcn_global_load_lds((const __attribute__((address_space(1))) void*)g,
                                     (__attribute__((address_space(3))) void*)l, 16, 0, 0);
}

// ---------------- prep A: LDS-tiled transpose of the two 768x768 weights ----------------
// 64x64 tiles, [64][65] pad: both global sides coalesced; LDS read stride-65 is
// conflict-free (bank = 65*tx % 32 = tx % 32, 2 lanes/bank = free).
__global__ __launch_bounds__(256) void prep_tr_kernel(
        const float* __restrict__ W0, const float* __restrict__ W1,
        u16* __restrict__ T0, u16* __restrict__ T1) {
    __shared__ float tile[64][65];
    const float* W = blockIdx.y ? W1 : W0;
    u16* T = blockIdx.y ? T1 : T0;
    const int bi = (blockIdx.x / 12) * 64;   // k-block (input row)
    const int bj = (blockIdx.x % 12) * 64;   // n-block (input col)
    const int tx = threadIdx.x & 63, ty = threadIdx.x >> 6;
#pragma unroll
    for (int r = 0; r < 64; r += 4)
        tile[r + ty][tx] = W[(size_t)(bi + r + ty) * 768 + bj + tx];
    __syncthreads();
#pragma unroll
    for (int r = 0; r < 64; r += 4)
        T[(size_t)(bj + r + ty) * 768 + bi + tx] = f2bf(tile[tx][r + ty]);
}

// ---------------- prep B: W_off|W_attn padded 128x768 -> woa_t + bias ----------------
__global__ void prep_oa_kernel(const float* __restrict__ Woff, const float* __restrict__ Wattn,
                               const float* __restrict__ boff, const float* __restrict__ battn,
                               u16* __restrict__ woa_t, float* __restrict__ bias) {
    int idx = blockIdx.x * 256 + threadIdx.x;
    if (idx >= 128 * K_DIM) return;
    int n = idx / K_DIM, k = idx - n * K_DIM;
    float v = 0.0f;
    if (n < 48)      v = Woff[(size_t)k * 48 + n];
    else if (n < 72) v = Wattn[(size_t)k * 24 + (n - 48)];
    woa_t[idx] = f2bf(v);
    if (idx < 128) bias[idx] = idx < 48 ? boff[idx] : (idx < 72 ? battn[idx - 48] : 0.0f);
}

// ---------------- LayerNorm: f32 in -> bf16 out (wave-per-row, no LDS/sync) ----------------
// nt input loads: 200 MB touch-once f32 must not evict L2/L3-resident data.
__global__ __launch_bounds__(256) void ln_kernel(const float* __restrict__ x,
                                                 const float* __restrict__ g,
                                                 const float* __restrict__ b,
                                                 u16* __restrict__ out) {
    const int row = blockIdx.x * 4 + (threadIdx.x >> 6);
    const int lane = threadIdx.x & 63;
    const f32x4v* xp = (const f32x4v*)(x + (size_t)row * K_DIM);
    f32x4v v[3];
    float s = 0.0f, s2 = 0.0f;
#pragma unroll
    for (int j = 0; j < 3; ++j) {
        v[j] = __builtin_nontemporal_load(xp + lane + 64 * j);
        s  += v[j].x + v[j].y + v[j].z + v[j].w;
        s2 += v[j].x * v[j].x + v[j].y * v[j].y + v[j].z * v[j].z + v[j].w * v[j].w;
    }
#pragma unroll
    for (int off = 32; off >= 1; off >>= 1) {
        s  += __shfl_xor(s, off);
        s2 += __shfl_xor(s2, off);
    }
    const float mean = s * (1.0f / K_DIM);
    const float var  = s2 * (1.0f / K_DIM) - mean * mean;
    const float inv  = rsqrtf(var + 1e-6f);
#pragma unroll
    for (int j = 0; j < 3; ++j) {
        const float4 gg = ((const float4*)g)[lane + 64 * j];
        const float4 bb = ((const float4*)b)[lane + 64 * j];
        ushort4 o;
        o.x = f2bf((v[j].x - mean) * inv * gg.x + bb.x);
        o.y = f2bf((v[j].y - mean) * inv * gg.y + bb.y);
        o.z = f2bf((v[j].z - mean) * inv * gg.z + bb.z);
        o.w = f2bf((v[j].w - mean) * inv * gg.w + bb.w);
        ((ushort4*)(out + (size_t)row * K_DIM))[lane + 64 * j] = o;
    }
}

// ---------------- MFMA GEMM: C[M][N] = A[M][768] * Bt[N][768]^T + bias ----------------
// R11/R13 best configuration: 128x128 tile (big GEMMs), BK=64, 8 waves (2Mx4N),
// 512 threads, 2 blocks/CU; 2-phase pipeline (dbuf LDS, stage(t+1) before compute(t),
// vmcnt(0) after MFMA); 32x32x16 MFMA. R12: BN=64/3-blocks regresses; R8: depth-2
// vmcnt regresses. C/D: col=lane&31, row=(reg&3)+8*(reg>>2)+4*(lane>>5) [m74/m101].
// XOR-swizzle (slot ^= row&7): linear LDS dest + inverse-swizzled global source.
// 1D grid + bijective XCD-chunked swizzle (nwg%8==0).
// nt epilogues: EP_FINAL query-load/out-store (R13, confirmed -14 MB FETCH);
// EP_VAL store (consumed a kernel later; keeps L2 clean for panel reuse).
#define EP_VAL 0
#define EP_OA 1
#define EP_FINAL 2

template <int EP, int NX, int BN = 128>
__global__ __launch_bounds__(512) void gemm_kernel(
        const u16* __restrict__ A, const u16* __restrict__ Bt,
        const float* __restrict__ bias, void* __restrict__ out, int ld_out,
        const float* __restrict__ query, const float* __restrict__ gamma) {
    constexpr int WN  = (BN >= 128) ? 4 : 2;   // wave grid: WM x WN, 8 waves
    constexpr int WM  = 8 / WN;
    constexpr int MW  = 128 / WM;              // wave m-extent (64 or 32)
    constexpr int MF  = MW / 32;               // 32x32 m-frags per wave (2 or 1)
    constexpr int BCH = BN / 64;               // B staging chunks per wave
    constexpr int BUF = 16384 + BN * 128;      // A tile 16 KB + B tile BN*128 B
    constexpr int NWG = NX * (M_ROWS / 128);
    constexpr int CPX = NWG / 8;
    __shared__ __align__(16) char smem[2 * BUF];
    const int lane = threadIdx.x & 63;
    const int wv = threadIdx.x >> 6;           // 0..7
    const int wr = wv / WN, wc = wv % WN;
    const int lr = lane & 31, hi = lane >> 5;
    const int wg  = blockIdx.x;
    const int swz = (wg & 7) * CPX + (wg >> 3);    // bijective: NWG % 8 == 0
    const int m0 = (swz / NX) * 128;               // n fastest within XCD chunk
    const int n0 = (swz % NX) * BN;

    f32x16 acc[MF] = {};

    const u16* Ab = A + (size_t)m0 * K_DIM;
    const u16* Bb = Bt + (size_t)n0 * K_DIM;

    auto stage = [&](char* buf, int kt) {
#pragma unroll
        for (int c = 0; c < 2; ++c) {               // A: 16 chunks / 8 waves
            int chunk = wv * 2 + c;                 // 0..15
            int row = chunk * 8 + (lane >> 3);      // 0..127
            int slot = (lane & 7) ^ (row & 7);      // pre-swizzled k-slot
            gload_lds16(Ab + (size_t)row * K_DIM + kt + slot * 8, buf + chunk * 1024);
        }
#pragma unroll
        for (int c = 0; c < BCH; ++c) {             // B: BN/8 chunks / 8 waves
            int chunk = wv * BCH + c;
            int row = chunk * 8 + (lane >> 3);      // 0..BN-1
            int slot = (lane & 7) ^ (row & 7);
            gload_lds16(Bb + (size_t)row * K_DIM + kt + slot * 8, buf + 16384 + chunk * 1024);
        }
    };

    // prologue: tile 0
    stage(smem, 0);
    asm volatile("s_waitcnt vmcnt(0)" ::: "memory");
    __builtin_amdgcn_s_barrier();
    __builtin_amdgcn_sched_barrier(0);

    constexpr int NT = K_DIM / 64;   // 12
    int cur = 0;
#pragma unroll 2
    for (int t = 0; t < NT; ++t) {
        const char* rb = smem + cur * BUF;
        if (t + 1 < NT) stage(smem + (cur ^ 1) * BUF, (t + 1) * 64);   // prefetch in flight
#pragma unroll
        for (int kk = 0; kk < 4; ++kk) {            // 4 x K=16 per K-step
            s16x8 af[MF], bfr;
#pragma unroll
            for (int mi = 0; mi < MF; ++mi) {
                int row = wr * MW + mi * 32 + lr;
                int slot = (kk * 2 + hi) ^ (row & 7);
                af[mi] = *(const s16x8*)(rb + row * 128 + slot * 16);
            }
            {
                int row = wc * 32 + lr;
                int slot = (kk * 2 + hi) ^ (row & 7);
                bfr = *(const s16x8*)(rb + 16384 + row * 128 + slot * 16);
            }
            __builtin_amdgcn_s_setprio(1);
#pragma unroll
            for (int mi = 0; mi < MF; ++mi)
                acc[mi] = __builtin_amdgcn_mfma_f32_32x32x16_bf16(af[mi], bfr, acc[mi], 0, 0, 0);
            __builtin_amdgcn_s_setprio(0);
        }
        // tile t+1 fully landed; all waves done reading rb
        asm volatile("s_waitcnt vmcnt(0)" ::: "memory");
        __builtin_amdgcn_s_barrier();
        __builtin_amdgcn_sched_barrier(0);
        cur ^= 1;
    }

    // epilogue; C/D: col = lane&31, row = (reg&3) + 8*(reg>>2) + 4*(lane>>5)  [m74/m101]
    const int col = n0 + wc * 32 + lr;
#pragma unroll
    for (int mi = 0; mi < MF; ++mi) {
#pragma unroll
        for (int reg = 0; reg < 16; ++reg) {
            int row = m0 + wr * MW + mi * 32 + (reg & 3) + 8 * (reg >> 2) + 4 * hi;
            float v = acc[mi][reg] + bias[col];
            if constexpr (EP == EP_VAL) {
                // head-planed: value[h][row][d], h = col>>7 (block-uniform), d = col&127
                __builtin_nontemporal_store(f2bf(v),
                    (u16*)out + ((size_t)(col >> 7) * M_ROWS + row) * 128 + (col & 127));
            } else if constexpr (EP == EP_OA) {
                if (col < 72) {   // compact per-head oa2[h][row][12]
                    int hh, s;
                    if (col < 48) { hh = col >> 3; s = col & 7; }
                    else          { hh = (col - 48) >> 2; s = 8 + ((col - 48) & 3); }
                    ((float*)out)[((size_t)hh * M_ROWS + row) * 12 + s] = v;
                }
            } else {
                size_t idx = (size_t)row * ld_out + col;
                float qv = __builtin_nontemporal_load(query + idx);      // touch-once stream
                __builtin_nontemporal_store(qv + gamma[col] * v, (float*)out + idx);
            }
        }
    }
}

// ---------------- bilinear sampling (head-phased) ----------------
// grid = 6 * 4096 blocks, h-major: block handles 8 consecutive q for ONE head.
// Blocks dispatch roughly in order -> all CUs gather from the same 8 MB head
// plane at a time (L2/L3-hot working set). Perf heuristic only.
// Per wave: lanes (mod 16) = corner; 1 exp/lane softmax; pack {bf16 weight |
// pos(14b)} -> one readlane/corner; 16 UNCONDITIONAL gathers (R4 lesson).
// nt output store: 50 MB consumed a kernel later; keep L2 for value gathers.
__global__ __launch_bounds__(512) void sample_kernel(
        const float* __restrict__ oa2,   // [6][32768][12]: 8 offsets + 4 logits
        const float* __restrict__ rp,    // [32768][2]
        const u16* __restrict__ value,   // [6][32768][128] bf16 head planes
        u16* __restrict__ samp) {        // [32768][768]
    const int h = blockIdx.x >> 12;                                  // 0..5
    const int q = __builtin_amdgcn_readfirstlane(
                      ((blockIdx.x & 4095) << 3) + (threadIdx.x >> 6));
    const int lane = threadIdx.x & 63;
    const int b = q >> 14;
    const float* oar = oa2 + ((size_t)h * M_ROWS + q) * 12;

    // ---- phase 1: corner c = lane&15; p = c>>2, cn = c&3
    const int p  = (lane >> 2) & 3;
    const int cn = lane & 3;
    const float lp = oar[8 + p];               // own point's logit only
    const float e  = __expf(lp);
    float es = e;
    es += __shfl_xor(es, 4);                   // sum over the 4 points
    es += __shfl_xor(es, 8);                   // (masks 4,8 stay within 16-group)
    const float aw = e * __builtin_amdgcn_rcpf(es);

    const float2 offv = *(const float2*)(oar + p * 2);            // per-lane (p)
    const float2 rpv  = *(const float2*)(rp + (size_t)q * 2);     // uniform
    const float xx = rpv.x * 128.0f + offv.x - 0.5f;
    const float yy = rpv.y * 128.0f + offv.y - 0.5f;
    const float x0 = floorf(xx), y0 = floorf(yy);
    const float fx = xx - x0, fy = yy - y0;
    const float cx = x0 + (float)(cn & 1);
    const float cy = y0 + (float)(cn >> 1);
    const float wx = (cn & 1) ? fx : 1.0f - fx;
    const float wy = (cn >> 1) ? fy : 1.0f - fy;
    const bool valid = (cx >= 0.0f) & (cx <= 127.0f) & (cy >= 0.0f) & (cy <= 127.0f);
    const float w = valid ? aw * wx * wy : 0.0f;
    const int cxi = (int)fminf(fmaxf(cx, 0.0f), 127.0f);
    const int cyi = (int)fminf(fmaxf(cy, 0.0f), 127.0f);
    // pack: truncated-bf16 weight bits [31:16] | pos (14 bits) [13:0]
    const int packed = (__float_as_int(w) & 0xffff0000) | (cyi * HW_ + cxi);

    // ---- phase 2: SGPR plane base; one readlane/corner; SALU extract
    const char* vbs = (const char*)value + ((size_t)h * M_ROWS + (size_t)b * NQ_) * 256;
    float acc0 = 0.0f, acc1 = 0.0f;
#pragma unroll
    for (int c = 0; c < 16; ++c) {
        const int pc = __builtin_amdgcn_readlane(packed, c);        // SGPR
        const float wc = __int_as_float(pc & 0xffff0000);           // SALU
        const int   oc = (pc & 0x3fff) << 8;                        // SALU: pos*256B
        const uint32_t d = ((const uint32_t*)(vbs + oc))[lane];
        acc0 = fmaf(wc, __int_as_float(d << 16), acc0);
        acc1 = fmaf(wc, __int_as_float(d), acc1);   // hi bf16 + low-mantissa garbage
    }
    const uint32_t ov = (uint32_t)f2bf(acc0) | ((uint32_t)f2bf(acc1) << 16);
    __builtin_nontemporal_store(ov,
        (uint32_t*)(samp + (size_t)q * K_DIM + h * 128) + lane);
}

// ---------------- launch ----------------
extern "C" void kernel_launch(void* const* d_in, const int* in_sizes, int n_in,
                              void* d_out, int out_size, void* d_ws, size_t ws_size,
                              hipStream_t stream) {
    (void)in_sizes; (void)n_in; (void)out_size; (void)ws_size;
    const float* query  = (const float*)d_in[0];
    const float* rp     = (const float*)d_in[1];
    const float* feat   = (const float*)d_in[2];
    const float* qn_g   = (const float*)d_in[5];
    const float* qn_b   = (const float*)d_in[6];
    const float* fn_g   = (const float*)d_in[7];
    const float* fn_b   = (const float*)d_in[8];
    const float* gamma  = (const float*)d_in[9];
    const float* W_off  = (const float*)d_in[10];
    const float* b_off  = (const float*)d_in[11];
    const float* W_attn = (const float*)d_in[12];
    const float* b_attn = (const float*)d_in[13];
    const float* W_val  = (const float*)d_in[14];
    const float* b_val  = (const float*)d_in[15];
    const float* W_out  = (const float*)d_in[16];
    const float* b_out  = (const float*)d_in[17];

    char* ws = (char*)d_ws;
    u16*   ln_buf  = (u16*)  (ws + 0);           // 50,331,648 B (reused for samp)
    u16*   val_buf = (u16*)  (ws + 50331648);    // 50,331,648 B (head planes [6][32768][128])
    float* oa2_buf = (float*)(ws + 100663296);   //  9,437,184 B ([6][32768][12])
    u16*   wv_t    = (u16*)  (ws + 117440512);   // 1,179,648 B
    u16*   wo_t    = (u16*)  (ws + 118620160);   // 1,179,648 B
    u16*   woa_t   = (u16*)  (ws + 119799808);   //   196,608 B
    float* bias_oa = (float*)(ws + 119996416);   //       512 B
    u16*   samp_buf = ln_buf;                    // q_ln dead once offattn GEMM finishes

    prep_tr_kernel<<<dim3(144, 2), 256, 0, stream>>>(W_val, W_out, wv_t, wo_t);
    prep_oa_kernel<<<(128 * 768 + 255) / 256, 256, 0, stream>>>(
        W_off, W_attn, b_off, b_attn, woa_t, bias_oa);

    ln_kernel<<<M_ROWS / 4, 256, 0, stream>>>(feat, fn_g, fn_b, ln_buf);

    gemm_kernel<EP_VAL, 6><<<6 * (M_ROWS / 128), 512, 0, stream>>>(ln_buf, wv_t, b_val, val_buf, 768, nullptr, nullptr);

    ln_kernel<<<M_ROWS / 4, 256, 0, stream>>>(query, qn_g, qn_b, ln_buf);

    gemm_kernel<EP_OA, 2, 64><<<2 * (M_ROWS / 128), 512, 0, stream>>>(ln_buf, woa_t, bias_oa, oa2_buf, 0, nullptr, nullptr);

    sample_kernel<<<6 * 4096, 512, 0, stream>>>(oa2_buf, rp, val_buf, samp_buf);

    gemm_kernel<EP_FINAL, 6><<<6 * (M_ROWS / 128), 512, 0, stream>>>(samp_buf, wo_t, b_out, d_out, 768, query, gamma);
}

// Round 16
// 240.984 us; speedup vs baseline: 1.0303x; 1.0303x over previous
//
#include <hip/hip_runtime.h>
#include <stdint.h>

typedef unsigned short u16;
typedef float f32x16 __attribute__((ext_vector_type(16)));
typedef float f32x4v __attribute__((ext_vector_type(4)));   // clang vector: nt-load legal
typedef short s16x8 __attribute__((ext_vector_type(8)));

#define K_DIM 768      // C = K for all GEMMs
#define M_ROWS 32768   // B*NQ
#define NQ_ 16384
#define HW_ 128

__device__ __forceinline__ float bf2f(u16 u) {
    union { uint32_t u; float f; } c; c.u = ((uint32_t)u) << 16; return c.f;
}
__device__ __forceinline__ u16 f2bf(float f) {
    union { float f; uint32_t u; } c; c.f = f;
    uint32_t u = c.u;
    u += 0x7FFFu + ((u >> 16) & 1);   // round-to-nearest-even
    return (u16)(u >> 16);
}

__device__ __forceinline__ void gload_lds16(const void* g, void* l) {
    __builtin_amdgcn_global_load_lds((const __attribute__((address_space(1))) void*)g,
                                     (__attribute__((address_space(3))) void*)l, 16, 0, 0);
}

// ---------------- prep A: LDS-tiled transpose of the two 768x768 weights ----------------
// 64x64 tiles, [64][65] pad: both global sides coalesced; LDS read stride-65 is
// conflict-free (bank = 65*tx % 32 = tx % 32, 2 lanes/bank = free).
__global__ __launch_bounds__(256) void prep_tr_kernel(
        const float* __restrict__ W0, const float* __restrict__ W1,
        u16* __restrict__ T0, u16* __restrict__ T1) {
    __shared__ float tile[64][65];
    const float* W = blockIdx.y ? W1 : W0;
    u16* T = blockIdx.y ? T1 : T0;
    const int bi = (blockIdx.x / 12) * 64;   // k-block (input row)
    const int bj = (blockIdx.x % 12) * 64;   // n-block (input col)
    const int tx = threadIdx.x & 63, ty = threadIdx.x >> 6;
#pragma unroll
    for (int r = 0; r < 64; r += 4)
        tile[r + ty][tx] = W[(size_t)(bi + r + ty) * 768 + bj + tx];
    __syncthreads();
#pragma unroll
    for (int r = 0; r < 64; r += 4)
        T[(size_t)(bj + r + ty) * 768 + bi + tx] = f2bf(tile[tx][r + ty]);
}

// ---------------- prep B: W_off|W_attn padded 128x768 -> woa_t + bias ----------------
__global__ void prep_oa_kernel(const float* __restrict__ Woff, const float* __restrict__ Wattn,
                               const float* __restrict__ boff, const float* __restrict__ battn,
                               u16* __restrict__ woa_t, float* __restrict__ bias) {
    int idx = blockIdx.x * 256 + threadIdx.x;
    if (idx >= 128 * K_DIM) return;
    int n = idx / K_DIM, k = idx - n * K_DIM;
    float v = 0.0f;
    if (n < 48)      v = Woff[(size_t)k * 48 + n];
    else if (n < 72) v = Wattn[(size_t)k * 24 + (n - 48)];
    woa_t[idx] = f2bf(v);
    if (idx < 128) bias[idx] = idx < 48 ? boff[idx] : (idx < 72 ? battn[idx - 48] : 0.0f);
}

// ---------------- LayerNorm: f32 in -> bf16 out (wave-per-row, no LDS/sync) ----------------
// nt input loads: 200 MB touch-once f32 (never re-read) must not evict L2/L3.
// Output store is NORMAL: ln_buf is consumed by the next GEMM (R15 lesson:
// nt-store on consumed data costs the consumer L2 hits, -13 us on EP_FINAL).
__global__ __launch_bounds__(256) void ln_kernel(const float* __restrict__ x,
                                                 const float* __restrict__ g,
                                                 const float* __restrict__ b,
                                                 u16* __restrict__ out) {
    const int row = blockIdx.x * 4 + (threadIdx.x >> 6);
    const int lane = threadIdx.x & 63;
    const f32x4v* xp = (const f32x4v*)(x + (size_t)row * K_DIM);
    f32x4v v[3];
    float s = 0.0f, s2 = 0.0f;
#pragma unroll
    for (int j = 0; j < 3; ++j) {
        v[j] = __builtin_nontemporal_load(xp + lane + 64 * j);
        s  += v[j].x + v[j].y + v[j].z + v[j].w;
        s2 += v[j].x * v[j].x + v[j].y * v[j].y + v[j].z * v[j].z + v[j].w * v[j].w;
    }
#pragma unroll
    for (int off = 32; off >= 1; off >>= 1) {
        s  += __shfl_xor(s, off);
        s2 += __shfl_xor(s2, off);
    }
    const float mean = s * (1.0f / K_DIM);
    const float var  = s2 * (1.0f / K_DIM) - mean * mean;
    const float inv  = rsqrtf(var + 1e-6f);
#pragma unroll
    for (int j = 0; j < 3; ++j) {
        const float4 gg = ((const float4*)g)[lane + 64 * j];
        const float4 bb = ((const float4*)b)[lane + 64 * j];
        ushort4 o;
        o.x = f2bf((v[j].x - mean) * inv * gg.x + bb.x);
        o.y = f2bf((v[j].y - mean) * inv * gg.y + bb.y);
        o.z = f2bf((v[j].z - mean) * inv * gg.z + bb.z);
        o.w = f2bf((v[j].w - mean) * inv * gg.w + bb.w);
        ((ushort4*)(out + (size_t)row * K_DIM))[lane + 64 * j] = o;
    }
}

// ---------------- MFMA GEMM: C[M][N] = A[M][768] * Bt[N][768]^T + bias ----------------
// R11/R13 best configuration: 128x128 tile (big GEMMs), BK=64, 8 waves (2Mx4N),
// 512 threads, 2 blocks/CU; 2-phase pipeline (dbuf LDS, stage(t+1) before compute(t),
// vmcnt(0) after MFMA); 32x32x16 MFMA. R12: BN=64/3-blocks regresses; R8: depth-2
// vmcnt regresses. C/D: col=lane&31, row=(reg&3)+8*(reg>>2)+4*(lane>>5) [m74/m101].
// XOR-swizzle (slot ^= row&7): linear LDS dest + inverse-swizzled global source.
// 1D grid + bijective XCD-chunked swizzle (nwg%8==0).
// nt ONLY on true touch-once streams: EP_FINAL query-load / out-store (R13 win).
// EP_VAL store is NORMAL — sample_kernel consumes it (R15 lesson).
#define EP_VAL 0
#define EP_OA 1
#define EP_FINAL 2

template <int EP, int NX, int BN = 128>
__global__ __launch_bounds__(512) void gemm_kernel(
        const u16* __restrict__ A, const u16* __restrict__ Bt,
        const float* __restrict__ bias, void* __restrict__ out, int ld_out,
        const float* __restrict__ query, const float* __restrict__ gamma) {
    constexpr int WN  = (BN >= 128) ? 4 : 2;   // wave grid: WM x WN, 8 waves
    constexpr int WM  = 8 / WN;
    constexpr int MW  = 128 / WM;              // wave m-extent (64 or 32)
    constexpr int MF  = MW / 32;               // 32x32 m-frags per wave (2 or 1)
    constexpr int BCH = BN / 64;               // B staging chunks per wave
    constexpr int BUF = 16384 + BN * 128;      // A tile 16 KB + B tile BN*128 B
    constexpr int NWG = NX * (M_ROWS / 128);
    constexpr int CPX = NWG / 8;
    __shared__ __align__(16) char smem[2 * BUF];
    const int lane = threadIdx.x & 63;
    const int wv = threadIdx.x >> 6;           // 0..7
    const int wr = wv / WN, wc = wv % WN;
    const int lr = lane & 31, hi = lane >> 5;
    const int wg  = blockIdx.x;
    const int swz = (wg & 7) * CPX + (wg >> 3);    // bijective: NWG % 8 == 0
    const int m0 = (swz / NX) * 128;               // n fastest within XCD chunk
    const int n0 = (swz % NX) * BN;

    f32x16 acc[MF] = {};

    const u16* Ab = A + (size_t)m0 * K_DIM;
    const u16* Bb = Bt + (size_t)n0 * K_DIM;

    auto stage = [&](char* buf, int kt) {
#pragma unroll
        for (int c = 0; c < 2; ++c) {               // A: 16 chunks / 8 waves
            int chunk = wv * 2 + c;                 // 0..15
            int row = chunk * 8 + (lane >> 3);      // 0..127
            int slot = (lane & 7) ^ (row & 7);      // pre-swizzled k-slot
            gload_lds16(Ab + (size_t)row * K_DIM + kt + slot * 8, buf + chunk * 1024);
        }
#pragma unroll
        for (int c = 0; c < BCH; ++c) {             // B: BN/8 chunks / 8 waves
            int chunk = wv * BCH + c;
            int row = chunk * 8 + (lane >> 3);      // 0..BN-1
            int slot = (lane & 7) ^ (row & 7);
            gload_lds16(Bb + (size_t)row * K_DIM + kt + slot * 8, buf + 16384 + chunk * 1024);
        }
    };

    // prologue: tile 0
    stage(smem, 0);
    asm volatile("s_waitcnt vmcnt(0)" ::: "memory");
    __builtin_amdgcn_s_barrier();
    __builtin_amdgcn_sched_barrier(0);

    constexpr int NT = K_DIM / 64;   // 12
    int cur = 0;
#pragma unroll 2
    for (int t = 0; t < NT; ++t) {
        const char* rb = smem + cur * BUF;
        if (t + 1 < NT) stage(smem + (cur ^ 1) * BUF, (t + 1) * 64);   // prefetch in flight
#pragma unroll
        for (int kk = 0; kk < 4; ++kk) {            // 4 x K=16 per K-step
            s16x8 af[MF], bfr;
#pragma unroll
            for (int mi = 0; mi < MF; ++mi) {
                int row = wr * MW + mi * 32 + lr;
                int slot = (kk * 2 + hi) ^ (row & 7);
                af[mi] = *(const s16x8*)(rb + row * 128 + slot * 16);
            }
            {
                int row = wc * 32 + lr;
                int slot = (kk * 2 + hi) ^ (row & 7);
                bfr = *(const s16x8*)(rb + 16384 + row * 128 + slot * 16);
            }
            __builtin_amdgcn_s_setprio(1);
#pragma unroll
            for (int mi = 0; mi < MF; ++mi)
                acc[mi] = __builtin_amdgcn_mfma_f32_32x32x16_bf16(af[mi], bfr, acc[mi], 0, 0, 0);
            __builtin_amdgcn_s_setprio(0);
        }
        // tile t+1 fully landed; all waves done reading rb
        asm volatile("s_waitcnt vmcnt(0)" ::: "memory");
        __builtin_amdgcn_s_barrier();
        __builtin_amdgcn_sched_barrier(0);
        cur ^= 1;
    }

    // epilogue; C/D: col = lane&31, row = (reg&3) + 8*(reg>>2) + 4*(lane>>5)  [m74/m101]
    const int col = n0 + wc * 32 + lr;
#pragma unroll
    for (int mi = 0; mi < MF; ++mi) {
#pragma unroll
        for (int reg = 0; reg < 16; ++reg) {
            int row = m0 + wr * MW + mi * 32 + (reg & 3) + 8 * (reg >> 2) + 4 * hi;
            float v = acc[mi][reg] + bias[col];
            if constexpr (EP == EP_VAL) {
                // head-planed: value[h][row][d], h = col>>7 (block-uniform), d = col&127
                // NORMAL store: consumed by sample_kernel (keep L2-warm)
                ((u16*)out)[((size_t)(col >> 7) * M_ROWS + row) * 128 + (col & 127)] = f2bf(v);
            } else if constexpr (EP == EP_OA) {
                if (col < 72) {   // compact per-head oa2[h][row][12]
                    int hh, s;
                    if (col < 48) { hh = col >> 3; s = col & 7; }
                    else          { hh = (col - 48) >> 2; s = 8 + ((col - 48) & 3); }
                    ((float*)out)[((size_t)hh * M_ROWS + row) * 12 + s] = v;
                }
            } else {
                size_t idx = (size_t)row * ld_out + col;
                float qv = __builtin_nontemporal_load(query + idx);      // touch-once stream
                __builtin_nontemporal_store(qv + gamma[col] * v, (float*)out + idx);
            }
        }
    }
}

// ---------------- bilinear sampling (head-phased) ----------------
// grid = 6 * 4096 blocks, h-major: block handles 8 consecutive q for ONE head.
// Blocks dispatch roughly in order -> all CUs gather from the same 8 MB head
// plane at a time (L2/L3-hot working set). Perf heuristic only.
// Per wave: lanes (mod 16) = corner; 1 exp/lane softmax; pack {bf16 weight |
// pos(14b)} -> one readlane/corner; 16 UNCONDITIONAL gathers (R4 lesson).
// Output store NORMAL: samp is EP_FINAL's A-operand (R15 lesson).
__global__ __launch_bounds__(512) void sample_kernel(
        const float* __restrict__ oa2,   // [6][32768][12]: 8 offsets + 4 logits
        const float* __restrict__ rp,    // [32768][2]
        const u16* __restrict__ value,   // [6][32768][128] bf16 head planes
        u16* __restrict__ samp) {        // [32768][768]
    const int h = blockIdx.x >> 12;                                  // 0..5
    const int q = __builtin_amdgcn_readfirstlane(
                      ((blockIdx.x & 4095) << 3) + (threadIdx.x >> 6));
    const int lane = threadIdx.x & 63;
    const int b = q >> 14;
    const float* oar = oa2 + ((size_t)h * M_ROWS + q) * 12;

    // ---- phase 1: corner c = lane&15; p = c>>2, cn = c&3
    const int p  = (lane >> 2) & 3;
    const int cn = lane & 3;
    const float lp = oar[8 + p];               // own point's logit only
    const float e  = __expf(lp);
    float es = e;
    es += __shfl_xor(es, 4);                   // sum over the 4 points
    es += __shfl_xor(es, 8);                   // (masks 4,8 stay within 16-group)
    const float aw = e * __builtin_amdgcn_rcpf(es);

    const float2 offv = *(const float2*)(oar + p * 2);            // per-lane (p)
    const float2 rpv  = *(const float2*)(rp + (size_t)q * 2);     // uniform
    const float xx = rpv.x * 128.0f + offv.x - 0.5f;
    const float yy = rpv.y * 128.0f + offv.y - 0.5f;
    const float x0 = floorf(xx), y0 = floorf(yy);
    const float fx = xx - x0, fy = yy - y0;
    const float cx = x0 + (float)(cn & 1);
    const float cy = y0 + (float)(cn >> 1);
    const float wx = (cn & 1) ? fx : 1.0f - fx;
    const float wy = (cn >> 1) ? fy : 1.0f - fy;
    const bool valid = (cx >= 0.0f) & (cx <= 127.0f) & (cy >= 0.0f) & (cy <= 127.0f);
    const float w = valid ? aw * wx * wy : 0.0f;
    const int cxi = (int)fminf(fmaxf(cx, 0.0f), 127.0f);
    const int cyi = (int)fminf(fmaxf(cy, 0.0f), 127.0f);
    // pack: truncated-bf16 weight bits [31:16] | pos (14 bits) [13:0]
    const int packed = (__float_as_int(w) & 0xffff0000) | (cyi * HW_ + cxi);

    // ---- phase 2: SGPR plane base; one readlane/corner; SALU extract
    const char* vbs = (const char*)value + ((size_t)h * M_ROWS + (size_t)b * NQ_) * 256;
    float acc0 = 0.0f, acc1 = 0.0f;
#pragma unroll
    for (int c = 0; c < 16; ++c) {
        const int pc = __builtin_amdgcn_readlane(packed, c);        // SGPR
        const float wc = __int_as_float(pc & 0xffff0000);           // SALU
        const int   oc = (pc & 0x3fff) << 8;                        // SALU: pos*256B
        const uint32_t d = ((const uint32_t*)(vbs + oc))[lane];
        acc0 = fmaf(wc, __int_as_float(d << 16), acc0);
        acc1 = fmaf(wc, __int_as_float(d), acc1);   // hi bf16 + low-mantissa garbage
    }
    ushort2 o; o.x = f2bf(acc0); o.y = f2bf(acc1);
    ((ushort2*)(samp + (size_t)q * K_DIM + h * 128))[lane] = o;
}

// ---------------- launch ----------------
extern "C" void kernel_launch(void* const* d_in, const int* in_sizes, int n_in,
                              void* d_out, int out_size, void* d_ws, size_t ws_size,
                              hipStream_t stream) {
    (void)in_sizes; (void)n_in; (void)out_size; (void)ws_size;
    const float* query  = (const float*)d_in[0];
    const float* rp     = (const float*)d_in[1];
    const float* feat   = (const float*)d_in[2];
    const float* qn_g   = (const float*)d_in[5];
    const float* qn_b   = (const float*)d_in[6];
    const float* fn_g   = (const float*)d_in[7];
    const float* fn_b   = (const float*)d_in[8];
    const float* gamma  = (const float*)d_in[9];
    const float* W_off  = (const float*)d_in[10];
    const float* b_off  = (const float*)d_in[11];
    const float* W_attn = (const float*)d_in[12];
    const float* b_attn = (const float*)d_in[13];
    const float* W_val  = (const float*)d_in[14];
    const float* b_val  = (const float*)d_in[15];
    const float* W_out  = (const float*)d_in[16];
    const float* b_out  = (const float*)d_in[17];

    char* ws = (char*)d_ws;
    u16*   ln_buf  = (u16*)  (ws + 0);           // 50,331,648 B (reused for samp)
    u16*   val_buf = (u16*)  (ws + 50331648);    // 50,331,648 B (head planes [6][32768][128])
    float* oa2_buf = (float*)(ws + 100663296);   //  9,437,184 B ([6][32768][12])
    u16*   wv_t    = (u16*)  (ws + 117440512);   // 1,179,648 B
    u16*   wo_t    = (u16*)  (ws + 118620160);   // 1,179,648 B
    u16*   woa_t   = (u16*)  (ws + 119799808);   //   196,608 B
    float* bias_oa = (float*)(ws + 119996416);   //       512 B
    u16*   samp_buf = ln_buf;                    // q_ln dead once offattn GEMM finishes

    prep_tr_kernel<<<dim3(144, 2), 256, 0, stream>>>(W_val, W_out, wv_t, wo_t);
    prep_oa_kernel<<<(128 * 768 + 255) / 256, 256, 0, stream>>>(
        W_off, W_attn, b_off, b_attn, woa_t, bias_oa);

    ln_kernel<<<M_ROWS / 4, 256, 0, stream>>>(feat, fn_g, fn_b, ln_buf);

    gemm_kernel<EP_VAL, 6><<<6 * (M_ROWS / 128), 512, 0, stream>>>(ln_buf, wv_t, b_val, val_buf, 768, nullptr, nullptr);

    ln_kernel<<<M_ROWS / 4, 256, 0, stream>>>(query, qn_g, qn_b, ln_buf);

    gemm_kernel<EP_OA, 2, 64><<<2 * (M_ROWS / 128), 512, 0, stream>>>(ln_buf, woa_t, bias_oa, oa2_buf, 0, nullptr, nullptr);

    sample_kernel<<<6 * 4096, 512, 0, stream>>>(oa2_buf, rp, val_buf, samp_buf);

    gemm_kernel<EP_FINAL, 6><<<6 * (M_ROWS / 128), 512, 0, stream>>>(samp_buf, wo_t, b_out, d_out, 768, query, gamma);
}

// Round 17
// 231.820 us; speedup vs baseline: 1.0710x; 1.0395x over previous
//
#include <hip/hip_runtime.h>
#include <stdint.h>

typedef unsigned short u16;
typedef float f32x16 __attribute__((ext_vector_type(16)));
typedef short s16x8 __attribute__((ext_vector_type(8)));

#define K_DIM 768      // C = K for all GEMMs
#define M_ROWS 32768   // B*NQ
#define NQ_ 16384
#define HW_ 128

__device__ __forceinline__ float bf2f(u16 u) {
    union { uint32_t u; float f; } c; c.u = ((uint32_t)u) << 16; return c.f;
}
__device__ __forceinline__ u16 f2bf(float f) {
    union { float f; uint32_t u; } c; c.f = f;
    uint32_t u = c.u;
    u += 0x7FFFu + ((u >> 16) & 1);   // round-to-nearest-even
    return (u16)(u >> 16);
}

__device__ __forceinline__ void gload_lds16(const void* g, void* l) {
    __builtin_amdgcn_global_load_lds((const __attribute__((address_space(1))) void*)g,
                                     (__attribute__((address_space(3))) void*)l, 16, 0, 0);
}

// ---------------- prep (single kernel): all weights -> bf16 B^T + oa bias ----------------
__global__ void prep_all_kernel(const float* __restrict__ Wval, const float* __restrict__ Wout,
                                const float* __restrict__ Woff, const float* __restrict__ Wattn,
                                const float* __restrict__ boff, const float* __restrict__ battn,
                                u16* __restrict__ wv_t, u16* __restrict__ wo_t,
                                u16* __restrict__ woa_t, float* __restrict__ bias) {
    int idx = blockIdx.x * 256 + threadIdx.x;
    const int SZ = 768 * K_DIM;
    if (idx < SZ) {
        int n = idx / K_DIM, k = idx - n * K_DIM;
        wv_t[idx] = f2bf(Wval[(size_t)k * 768 + n]);
    } else if (idx < 2 * SZ) {
        int r = idx - SZ;
        int n = r / K_DIM, k = r - n * K_DIM;
        wo_t[r] = f2bf(Wout[(size_t)k * 768 + n]);
    } else if (idx < 2 * SZ + 128 * K_DIM) {
        int r = idx - 2 * SZ;
        int n = r / K_DIM, k = r - n * K_DIM;
        float v = 0.0f;
        if (n < 48)      v = Woff[(size_t)k * 48 + n];
        else if (n < 72) v = Wattn[(size_t)k * 24 + (n - 48)];
        woa_t[r] = f2bf(v);
        if (r < 128) bias[r] = r < 48 ? boff[r] : (r < 72 ? battn[r - 48] : 0.0f);
    }
}

// ---------------- LayerNorm: f32 in -> bf16 out (wave-per-row, no LDS/sync) ----------------
__global__ __launch_bounds__(256) void ln_kernel(const float* __restrict__ x,
                                                 const float* __restrict__ g,
                                                 const float* __restrict__ b,
                                                 u16* __restrict__ out) {
    const int row = blockIdx.x * 4 + (threadIdx.x >> 6);
    const int lane = threadIdx.x & 63;
    float4 v[3];
    float s = 0.0f, s2 = 0.0f;
#pragma unroll
    for (int j = 0; j < 3; ++j) {
        v[j] = ((const float4*)(x + (size_t)row * K_DIM))[lane + 64 * j];
        s  += v[j].x + v[j].y + v[j].z + v[j].w;
        s2 += v[j].x * v[j].x + v[j].y * v[j].y + v[j].z * v[j].z + v[j].w * v[j].w;
    }
#pragma unroll
    for (int off = 32; off >= 1; off >>= 1) {
        s  += __shfl_xor(s, off);
        s2 += __shfl_xor(s2, off);
    }
    const float mean = s * (1.0f / K_DIM);
    const float var  = s2 * (1.0f / K_DIM) - mean * mean;
    const float inv  = rsqrtf(var + 1e-6f);
#pragma unroll
    for (int j = 0; j < 3; ++j) {
        const float4 gg = ((const float4*)g)[lane + 64 * j];
        const float4 bb = ((const float4*)b)[lane + 64 * j];
        ushort4 o;
        o.x = f2bf((v[j].x - mean) * inv * gg.x + bb.x);
        o.y = f2bf((v[j].y - mean) * inv * gg.y + bb.y);
        o.z = f2bf((v[j].z - mean) * inv * gg.z + bb.z);
        o.w = f2bf((v[j].w - mean) * inv * gg.w + bb.w);
        ((ushort4*)(out + (size_t)row * K_DIM))[lane + 64 * j] = o;
    }
}

// ---------------- MFMA GEMM: C[M][N] = A[M][768] * Bt[N][768]^T + bias ----------------
// Measured-best configuration (R13, 232.7 us): 128x128 tile (big GEMMs), BK=64,
// 8 waves (2Mx4N), 512 threads, 2 blocks/CU; 2-phase pipeline (dbuf LDS,
// stage(t+1) before compute(t), vmcnt(0) after MFMA); 32x32x16 MFMA.
// Bracketed regressions: BN=64/3-blocks (R12), depth-2 counted vmcnt (R8),
// nt-store on consumed buffers (R15), LN nt-loads (R16).
// C/D: col=lane&31, row=(reg&3)+8*(reg>>2)+4*(lane>>5) [m74/m101-verified].
// XOR-swizzle (slot ^= row&7): linear LDS dest + inverse-swizzled global source.
// 1D grid + bijective XCD-chunked swizzle (nwg%8==0).
// nt ONLY on true touch-once streams: EP_FINAL query-load / out-store (R13 win).
#define EP_VAL 0
#define EP_OA 1
#define EP_FINAL 2

template <int EP, int NX, int BN = 128>
__global__ __launch_bounds__(512) void gemm_kernel(
        const u16* __restrict__ A, const u16* __restrict__ Bt,
        const float* __restrict__ bias, void* __restrict__ out, int ld_out,
        const float* __restrict__ query, const float* __restrict__ gamma) {
    constexpr int WN  = (BN >= 128) ? 4 : 2;   // wave grid: WM x WN, 8 waves
    constexpr int WM  = 8 / WN;
    constexpr int MW  = 128 / WM;              // wave m-extent (64 or 32)
    constexpr int MF  = MW / 32;               // 32x32 m-frags per wave (2 or 1)
    constexpr int BCH = BN / 64;               // B staging chunks per wave
    constexpr int BUF = 16384 + BN * 128;      // A tile 16 KB + B tile BN*128 B
    constexpr int NWG = NX * (M_ROWS / 128);
    constexpr int CPX = NWG / 8;
    __shared__ __align__(16) char smem[2 * BUF];
    const int lane = threadIdx.x & 63;
    const int wv = threadIdx.x >> 6;           // 0..7
    const int wr = wv / WN, wc = wv % WN;
    const int lr = lane & 31, hi = lane >> 5;
    const int wg  = blockIdx.x;
    const int swz = (wg & 7) * CPX + (wg >> 3);    // bijective: NWG % 8 == 0
    const int m0 = (swz / NX) * 128;               // n fastest within XCD chunk
    const int n0 = (swz % NX) * BN;

    f32x16 acc[MF] = {};

    const u16* Ab = A + (size_t)m0 * K_DIM;
    const u16* Bb = Bt + (size_t)n0 * K_DIM;

    auto stage = [&](char* buf, int kt) {
#pragma unroll
        for (int c = 0; c < 2; ++c) {               // A: 16 chunks / 8 waves
            int chunk = wv * 2 + c;                 // 0..15
            int row = chunk * 8 + (lane >> 3);      // 0..127
            int slot = (lane & 7) ^ (row & 7);      // pre-swizzled k-slot
            gload_lds16(Ab + (size_t)row * K_DIM + kt + slot * 8, buf + chunk * 1024);
        }
#pragma unroll
        for (int c = 0; c < BCH; ++c) {             // B: BN/8 chunks / 8 waves
            int chunk = wv * BCH + c;
            int row = chunk * 8 + (lane >> 3);      // 0..BN-1
            int slot = (lane & 7) ^ (row & 7);
            gload_lds16(Bb + (size_t)row * K_DIM + kt + slot * 8, buf + 16384 + chunk * 1024);
        }
    };

    // prologue: tile 0
    stage(smem, 0);
    asm volatile("s_waitcnt vmcnt(0)" ::: "memory");
    __builtin_amdgcn_s_barrier();
    __builtin_amdgcn_sched_barrier(0);

    constexpr int NT = K_DIM / 64;   // 12
    int cur = 0;
#pragma unroll 2
    for (int t = 0; t < NT; ++t) {
        const char* rb = smem + cur * BUF;
        if (t + 1 < NT) stage(smem + (cur ^ 1) * BUF, (t + 1) * 64);   // prefetch in flight
#pragma unroll
        for (int kk = 0; kk < 4; ++kk) {            // 4 x K=16 per K-step
            s16x8 af[MF], bfr;
#pragma unroll
            for (int mi = 0; mi < MF; ++mi) {
                int row = wr * MW + mi * 32 + lr;
                int slot = (kk * 2 + hi) ^ (row & 7);
                af[mi] = *(const s16x8*)(rb + row * 128 + slot * 16);
            }
            {
                int row = wc * 32 + lr;
                int slot = (kk * 2 + hi) ^ (row & 7);
                bfr = *(const s16x8*)(rb + 16384 + row * 128 + slot * 16);
            }
            __builtin_amdgcn_s_setprio(1);
#pragma unroll
            for (int mi = 0; mi < MF; ++mi)
                acc[mi] = __builtin_amdgcn_mfma_f32_32x32x16_bf16(af[mi], bfr, acc[mi], 0, 0, 0);
            __builtin_amdgcn_s_setprio(0);
        }
        // tile t+1 fully landed; all waves done reading rb
        asm volatile("s_waitcnt vmcnt(0)" ::: "memory");
        __builtin_amdgcn_s_barrier();
        __builtin_amdgcn_sched_barrier(0);
        cur ^= 1;
    }

    // epilogue; C/D: col = lane&31, row = (reg&3) + 8*(reg>>2) + 4*(lane>>5)  [m74/m101]
    const int col = n0 + wc * 32 + lr;
#pragma unroll
    for (int mi = 0; mi < MF; ++mi) {
#pragma unroll
        for (int reg = 0; reg < 16; ++reg) {
            int row = m0 + wr * MW + mi * 32 + (reg & 3) + 8 * (reg >> 2) + 4 * hi;
            float v = acc[mi][reg] + bias[col];
            if constexpr (EP == EP_VAL) {
                // head-planed: value[h][row][d], h = col>>7 (block-uniform), d = col&127
                ((u16*)out)[((size_t)(col >> 7) * M_ROWS + row) * 128 + (col & 127)] = f2bf(v);
            } else if constexpr (EP == EP_OA) {
                if (col < 72) {   // compact per-head oa2[h][row][12]
                    int hh, s;
                    if (col < 48) { hh = col >> 3; s = col & 7; }
                    else          { hh = (col - 48) >> 2; s = 8 + ((col - 48) & 3); }
                    ((float*)out)[((size_t)hh * M_ROWS + row) * 12 + s] = v;
                }
            } else {
                size_t idx = (size_t)row * ld_out + col;
                float qv = __builtin_nontemporal_load(query + idx);      // touch-once stream
                __builtin_nontemporal_store(qv + gamma[col] * v, (float*)out + idx);
            }
        }
    }
}

// ---------------- bilinear sampling (head-phased) ----------------
// grid = 6 * 4096 blocks, h-major: block handles 8 consecutive q for ONE head.
// Blocks dispatch roughly in order -> all CUs gather from the same 8 MB head
// plane at a time (L2/L3-hot working set). Perf heuristic only.
// Per wave: lanes (mod 16) = corner; 1 exp/lane softmax; pack {bf16 weight |
// pos(14b)} -> one readlane/corner; 16 UNCONDITIONAL gathers (R4 lesson).
__global__ __launch_bounds__(512) void sample_kernel(
        const float* __restrict__ oa2,   // [6][32768][12]: 8 offsets + 4 logits
        const float* __restrict__ rp,    // [32768][2]
        const u16* __restrict__ value,   // [6][32768][128] bf16 head planes
        u16* __restrict__ samp) {        // [32768][768]
    const int h = blockIdx.x >> 12;                                  // 0..5
    const int q = __builtin_amdgcn_readfirstlane(
                      ((blockIdx.x & 4095) << 3) + (threadIdx.x >> 6));
    const int lane = threadIdx.x & 63;
    const int b = q >> 14;
    const float* oar = oa2 + ((size_t)h * M_ROWS + q) * 12;

    // ---- phase 1: corner c = lane&15; p = c>>2, cn = c&3
    const int p  = (lane >> 2) & 3;
    const int cn = lane & 3;
    const float lp = oar[8 + p];               // own point's logit only
    const float e  = __expf(lp);
    float es = e;
    es += __shfl_xor(es, 4);                   // sum over the 4 points
    es += __shfl_xor(es, 8);                   // (masks 4,8 stay within 16-group)
    const float aw = e * __builtin_amdgcn_rcpf(es);

    const float2 offv = *(const float2*)(oar + p * 2);            // per-lane (p)
    const float2 rpv  = *(const float2*)(rp + (size_t)q * 2);     // uniform
    const float xx = rpv.x * 128.0f + offv.x - 0.5f;
    const float yy = rpv.y * 128.0f + offv.y - 0.5f;
    const float x0 = floorf(xx), y0 = floorf(yy);
    const float fx = xx - x0, fy = yy - y0;
    const float cx = x0 + (float)(cn & 1);
    const float cy = y0 + (float)(cn >> 1);
    const float wx = (cn & 1) ? fx : 1.0f - fx;
    const float wy = (cn >> 1) ? fy : 1.0f - fy;
    const bool valid = (cx >= 0.0f) & (cx <= 127.0f) & (cy >= 0.0f) & (cy <= 127.0f);
    const float w = valid ? aw * wx * wy : 0.0f;
    const int cxi = (int)fminf(fmaxf(cx, 0.0f), 127.0f);
    const int cyi = (int)fminf(fmaxf(cy, 0.0f), 127.0f);
    // pack: truncated-bf16 weight bits [31:16] | pos (14 bits) [13:0]
    const int packed = (__float_as_int(w) & 0xffff0000) | (cyi * HW_ + cxi);

    // ---- phase 2: SGPR plane base; one readlane/corner; SALU extract
    const char* vbs = (const char*)value + ((size_t)h * M_ROWS + (size_t)b * NQ_) * 256;
    float acc0 = 0.0f, acc1 = 0.0f;
#pragma unroll
    for (int c = 0; c < 16; ++c) {
        const int pc = __builtin_amdgcn_readlane(packed, c);        // SGPR
        const float wc = __int_as_float(pc & 0xffff0000);           // SALU
        const int   oc = (pc & 0x3fff) << 8;                        // SALU: pos*256B
        const uint32_t d = ((const uint32_t*)(vbs + oc))[lane];
        acc0 = fmaf(wc, __int_as_float(d << 16), acc0);
        acc1 = fmaf(wc, __int_as_float(d), acc1);   // hi bf16 + low-mantissa garbage
    }
    ushort2 o; o.x = f2bf(acc0); o.y = f2bf(acc1);
    ((ushort2*)(samp + (size_t)q * K_DIM + h * 128))[lane] = o;
}

// ---------------- launch ----------------
extern "C" void kernel_launch(void* const* d_in, const int* in_sizes, int n_in,
                              void* d_out, int out_size, void* d_ws, size_t ws_size,
                              hipStream_t stream) {
    (void)in_sizes; (void)n_in; (void)out_size; (void)ws_size;
    const float* query  = (const float*)d_in[0];
    const float* rp     = (const float*)d_in[1];
    const float* feat   = (const float*)d_in[2];
    const float* qn_g   = (const float*)d_in[5];
    const float* qn_b   = (const float*)d_in[6];
    const float* fn_g   = (const float*)d_in[7];
    const float* fn_b   = (const float*)d_in[8];
    const float* gamma  = (const float*)d_in[9];
    const float* W_off  = (const float*)d_in[10];
    const float* b_off  = (const float*)d_in[11];
    const float* W_attn = (const float*)d_in[12];
    const float* b_attn = (const float*)d_in[13];
    const float* W_val  = (const float*)d_in[14];
    const float* b_val  = (const float*)d_in[15];
    const float* W_out  = (const float*)d_in[16];
    const float* b_out  = (const float*)d_in[17];

    char* ws = (char*)d_ws;
    u16*   ln_buf  = (u16*)  (ws + 0);           // 50,331,648 B (reused for samp)
    u16*   val_buf = (u16*)  (ws + 50331648);    // 50,331,648 B (head planes [6][32768][128])
    float* oa2_buf = (float*)(ws + 100663296);   //  9,437,184 B ([6][32768][12])
    u16*   wv_t    = (u16*)  (ws + 117440512);   // 1,179,648 B
    u16*   wo_t    = (u16*)  (ws + 118620160);   // 1,179,648 B
    u16*   woa_t   = (u16*)  (ws + 119799808);   //   196,608 B
    float* bias_oa = (float*)(ws + 119996416);   //       512 B
    u16*   samp_buf = ln_buf;                    // q_ln dead once offattn GEMM finishes

    prep_all_kernel<<<(2 * 768 * 768 + 128 * 768 + 255) / 256, 256, 0, stream>>>(
        W_val, W_out, W_off, W_attn, b_off, b_attn, wv_t, wo_t, woa_t, bias_oa);

    ln_kernel<<<M_ROWS / 4, 256, 0, stream>>>(feat, fn_g, fn_b, ln_buf);

    gemm_kernel<EP_VAL, 6><<<6 * (M_ROWS / 128), 512, 0, stream>>>(ln_buf, wv_t, b_val, val_buf, 768, nullptr, nullptr);

    ln_kernel<<<M_ROWS / 4, 256, 0, stream>>>(query, qn_g, qn_b, ln_buf);

    gemm_kernel<EP_OA, 2, 64><<<2 * (M_ROWS / 128), 512, 0, stream>>>(ln_buf, woa_t, bias_oa, oa2_buf, 0, nullptr, nullptr);

    sample_kernel<<<6 * 4096, 512, 0, stream>>>(oa2_buf, rp, val_buf, samp_buf);

    gemm_kernel<EP_FINAL, 6><<<6 * (M_ROWS / 128), 512, 0, stream>>>(samp_buf, wo_t, b_out, d_out, 768, query, gamma);
}